// Round 3
// baseline (205.769 us; speedup 1.0000x reference)
//
#include <hip/hip_runtime.h>
#include <math.h>

#define BB 4
#define NN 2048
#define MM 2048
#define HEADS 8
#define DH 64

typedef _Float16 f16;
typedef _Float16 f16x4 __attribute__((ext_vector_type(4)));
typedef _Float16 f16x8 __attribute__((ext_vector_type(8)));
typedef float f32x4 __attribute__((ext_vector_type(4)));
typedef unsigned short ushort;

#define LOG2E 1.44269504088896f
#define QSCALE (0.125f * LOG2E)

#if __has_builtin(__builtin_amdgcn_exp2f)
#define EXP2(x) __builtin_amdgcn_exp2f(x)
#else
#define EXP2(x) exp2f(x)
#endif

__device__ __forceinline__ f16x4 pk4(float a, float b, float c, float d) {
#if __has_builtin(__builtin_amdgcn_cvt_pkrtz)
    auto t0 = __builtin_amdgcn_cvt_pkrtz(a, b);
    auto t1 = __builtin_amdgcn_cvt_pkrtz(c, d);
    f16x4 r;
    r[0] = t0[0]; r[1] = t0[1]; r[2] = t1[0]; r[3] = t1[1];
    return r;
#else
    f16x4 r = {(f16)a, (f16)b, (f16)c, (f16)d};
    return r;
#endif
}

// async global->LDS, 16B per lane, dest = wave-uniform base + lane*16
__device__ __forceinline__ void gl16(const void* g, void* l) {
    __builtin_amdgcn_global_load_lds(
        (const __attribute__((address_space(1))) unsigned int*)g,
        (__attribute__((address_space(3))) unsigned int*)l, 16, 0, 0);
}

// ---------------------------------------------------------------------------
// Fused weight prep + cmask->f32 bias.
// blocks [0,128) Wq, [128,384) Wkv, [384,512) Wo (hi/lo), [512,516) cbias.
// cbias[b][j] = cmask ? 0 : -1e30  (score init becomes one v_mul in attn_k).
// ---------------------------------------------------------------------------
__global__ void wprep_k(const float* __restrict__ Wq, const float* __restrict__ Wkv,
                        const float* __restrict__ Wo, const int* __restrict__ cmask,
                        f16* __restrict__ wq16, f16* __restrict__ wkv16,
                        f16* __restrict__ woh, f16* __restrict__ wol,
                        float* __restrict__ cbias)
{
    __shared__ f16 S0[64 * 36], S1[64 * 36];
    const int tid = threadIdx.x;
    const int bid = blockIdx.x;
    if (bid >= 512) {                       // cbias: 4 blocks x 256 thr x 8 j
        const int bb = bid - 512, j0 = tid * 8;
        int4 m0 = *(const int4*)(cmask + (size_t)bb * MM + j0);
        int4 m1 = *(const int4*)(cmask + (size_t)bb * MM + j0 + 4);
        float4 o0, o1;
        o0.x = m0.x ? 0.f : -1e30f; o0.y = m0.y ? 0.f : -1e30f;
        o0.z = m0.z ? 0.f : -1e30f; o0.w = m0.w ? 0.f : -1e30f;
        o1.x = m1.x ? 0.f : -1e30f; o1.y = m1.y ? 0.f : -1e30f;
        o1.z = m1.z ? 0.f : -1e30f; o1.w = m1.w ? 0.f : -1e30f;
        *(float4*)(cbias + (size_t)bb * MM + j0)     = o0;
        *(float4*)(cbias + (size_t)bb * MM + j0 + 4) = o1;
        return;
    }
    const int K = 512;
    const float* W; int N; f16* T16; f16 *Th, *Tl; int id;
    if (bid < 128)      { W = Wq;  N = 512;  T16 = wq16;  Th = 0; Tl = 0; id = bid; }
    else if (bid < 384) { W = Wkv; N = 1024; T16 = wkv16; Th = 0; Tl = 0; id = bid - 128; }
    else                { W = Wo;  N = 512;  T16 = 0; Th = woh; Tl = wol; id = bid - 384; }
    const int k0 = (id & 15) * 32, n0 = (id >> 4) * 64;
    const int kr = tid >> 3, nc = (tid & 7) * 8;
    float4 v0 = *(const float4*)(W + (size_t)(k0 + kr) * N + n0 + nc);
    float4 v1 = *(const float4*)(W + (size_t)(k0 + kr) * N + n0 + nc + 4);
    float e[8] = {v0.x, v0.y, v0.z, v0.w, v1.x, v1.y, v1.z, v1.w};
    const int n = tid >> 2, kc = (tid & 3) * 8;
    if (T16) {
#pragma unroll
        for (int j = 0; j < 8; j++) S0[(nc + j) * 36 + kr] = (f16)e[j];
        __syncthreads();
        *(uint4*)(T16 + (size_t)(n0 + n) * K + k0 + kc) = *(const uint4*)(S0 + n * 36 + kc);
    } else {
#pragma unroll
        for (int j = 0; j < 8; j++) {
            f16 h = (f16)e[j];
            S0[(nc + j) * 36 + kr] = h;
            S1[(nc + j) * 36 + kr] = (f16)(e[j] - (float)h);
        }
        __syncthreads();
        *(uint4*)(Th + (size_t)(n0 + n) * K + k0 + kc) = *(const uint4*)(S0 + n * 36 + kc);
        *(uint4*)(Tl + (size_t)(n0 + n) * K + k0 + kc) = *(const uint4*)(S1 + n * 36 + kc);
    }
}

// ---------------------------------------------------------------------------
// x/ctx f32 -> f16 (outputs live in the then-dead Opf region).
// 4096 blocks x 256 threads x 8 elems = 8,388,608 = |x|+|ctx|.
// ---------------------------------------------------------------------------
__global__ void xprep_k(const float* __restrict__ x, const float* __restrict__ ctx,
                        f16* __restrict__ xf, f16* __restrict__ cf)
{
    const size_t S = (size_t)BB * NN * 512;
    const size_t i = ((size_t)blockIdx.x * 256 + threadIdx.x) * 8;
    const float* src = (i < S) ? x + i : ctx + (i - S);
    f16* dst         = (i < S) ? xf + i : cf + (i - S);
    float4 v0 = *(const float4*)(src);
    float4 v1 = *(const float4*)(src + 4);
    f16x8 o;
    o[0] = (f16)v0.x; o[1] = (f16)v0.y; o[2] = (f16)v0.z; o[3] = (f16)v0.w;
    o[4] = (f16)v1.x; o[5] = (f16)v1.y; o[6] = (f16)v1.z; o[7] = (f16)v1.w;
    *(f16x8*)dst = o;
}

// ---------------------------------------------------------------------------
// Fused projections: 128x128 tiles, grid (64, 12). A is now pre-converted f16
// (xf/cf) -> A staging is a straight uint4 copy like the B path (half the
// fetch bytes, no cvt_pkrtz packing).
// by 0..3 : Q = tanh(x@Wq)*QSCALE -> qws; by 4..11: K=tanh->kws / V->vt[d][m]
// ---------------------------------------------------------------------------
__launch_bounds__(256)
__global__ void proj_k(const f16* __restrict__ xf, const f16* __restrict__ cf,
                       const f16* __restrict__ wq16, const f16* __restrict__ wkv16,
                       f16* __restrict__ qws, f16* __restrict__ kws, f16* __restrict__ vt)
{
    __shared__ f16 sA[128 * 36];
    __shared__ f16 sB[128 * 36];

    const int tid  = threadIdx.x;
    const int wave = tid >> 6, lane = tid & 63;
    const int l15  = lane & 15, quad = lane >> 4;
    const int by = blockIdx.y;
    const int isQ = (by < 4);
    const f16* A16 = isQ ? xf : cf;
    const f16* Bt  = isQ ? wq16 : wkv16;
    const int c0 = (isQ ? by : by - 4) * 128;
    const size_t r0 = (size_t)blockIdx.x * 128;
    const int K = 512;

    const int ar = tid >> 1;
    const int ac = (tid & 1) * 16;

    f32x4 acc[2][8] = {};

    for (int k0 = 0; k0 < K; k0 += 32) {
        uint4 av0 = *(const uint4*)(A16 + (r0 + ar) * K + k0 + ac);
        uint4 av1 = *(const uint4*)(A16 + (r0 + ar) * K + k0 + ac + 8);
        uint4 bv0 = *(const uint4*)(Bt + (size_t)(c0 + ar) * K + k0 + ac);
        uint4 bv1 = *(const uint4*)(Bt + (size_t)(c0 + ar) * K + k0 + ac + 8);
        __syncthreads();
        *(uint4*)(sA + ar * 36 + ac)     = av0;
        *(uint4*)(sA + ar * 36 + ac + 8) = av1;
        *(uint4*)(sB + ar * 36 + ac)     = bv0;
        *(uint4*)(sB + ar * 36 + ac + 8) = bv1;
        __syncthreads();

        f16x8 a[2];
#pragma unroll
        for (int rt = 0; rt < 2; rt++)
            a[rt] = *(const f16x8*)(sA + (wave * 32 + rt * 16 + l15) * 36 + quad * 8);
#pragma unroll
        for (int half = 0; half < 2; half++) {
            f16x8 b[4];
#pragma unroll
            for (int c = 0; c < 4; c++)
                b[c] = *(const f16x8*)(sB + ((half * 4 + c) * 16 + l15) * 36 + quad * 8);
#pragma unroll
            for (int rt = 0; rt < 2; rt++)
#pragma unroll
                for (int c = 0; c < 4; c++)
                    acc[rt][half * 4 + c] = __builtin_amdgcn_mfma_f32_16x16x32_f16(
                        a[rt], b[c], acc[rt][half * 4 + c], 0, 0, 0);
        }
    }

    const int b    = (int)(r0 >> 11);
    const int rloc = ((int)(r0 & 2047)) + wave * 32;

#pragma unroll
    for (int rt = 0; rt < 2; rt++)
#pragma unroll
        for (int ct = 0; ct < 8; ct++) {
            const int col = c0 + ct * 16 + l15;
            if (isQ || col < 512) {
                const int h = (col >> 6) & 7;
                const int d = col & 63;
                f16* dst = isQ ? qws : kws;
                const float sc = isQ ? QSCALE : 1.0f;
#pragma unroll
                for (int reg = 0; reg < 4; reg++) {
                    const int nn = rloc + rt * 16 + quad * 4 + reg;
                    dst[(((size_t)b * 8 + h) * 2048 + nn) * 64 + d] =
                        (f16)(tanhf(acc[rt][ct][reg]) * sc);
                }
            } else {
                const int c = col - 512;
                const int h = c >> 6;
                const int d = c & 63;
                const int m0 = rloc + rt * 16 + quad * 4;
                f16x4 pk;
#pragma unroll
                for (int reg = 0; reg < 4; reg++) pk[reg] = (f16)acc[rt][ct][reg];
                *(f16x4*)(vt + (((size_t)b * 8 + h) * 64 + d) * 2048 + m0) = pk;
            }
        }
}

// ---------------------------------------------------------------------------
// MFMA fp16 flash attention v10: single {vmcnt(0); s_barrier} per 64-j tile,
// DMA prefetch issued AFTER the barrier so the compiler's wait for the cbias
// loads is vmcnt(4) and the prefetch stays in flight through the whole
// compute phase. Race check: top barrier guarantees all waves drained DMA(i)
// and finished compute(i-1) before DMA(i+1) writes buf(i^1).
// Score init is one v_mul: st = cbias[j] * rowOkf (cbias precomputed).
// j-loop unrolled x2 so LDS buffer bases are compile-time constants.
// ---------------------------------------------------------------------------
__launch_bounds__(256, 4)
__global__ void attn_k(const f16* __restrict__ qws, const f16* __restrict__ kws,
                       const f16* __restrict__ vtws,
                       const int* __restrict__ mask, const float* __restrict__ cbias,
                       const float* __restrict__ nk, const float* __restrict__ nv,
                       f16* __restrict__ Opf, float* __restrict__ lp)
{
    __shared__ __align__(16) char smem[32768];   // [2][ K:8192 | V:8192 ]

    const int tid  = threadIdx.x;
    const int wave = tid >> 6, lane = tid & 63;
    const int l15  = lane & 15, quad = lane >> 4;
    const int bh = blockIdx.x, b = bh >> 3, h = bh & 7;
    const int q0 = blockIdx.y * 128 + wave * 32;
    const int jh = blockIdx.z;
    const int jbeg = jh << 9;

    const f16* kg0 = kws + (size_t)bh * MM * DH;
    const f16* vg0 = vtws + (size_t)bh * DH * MM;

    // staging geometry: dest linear (base + lane*16); source chunk
    // pre-swizzled by row&7 (involution matches the read-side XOR).
    const int lrow = lane >> 3;
    const int lsw  = ((lane & 7) ^ lrow) << 4;
    const char* kP = (const char*)kg0 + (size_t)(jbeg + wave * 16 + lrow) * 128 + lsw;
    const char* vP = (const char*)vg0 + (size_t)(wave * 16 + lrow) * 4096
                   + (size_t)jbeg * 2 + lsw;
    char* kD = smem + wave * 2048;
    char* vD = smem + 8192 + wave * 2048;

    // prologue: DMA tile 0 into buf0 (latency hidden under q/pnull setup)
    gl16(kP,         kD);
    gl16(kP + 1024,  kD + 1024);
    gl16(vP,         vD);
    gl16(vP + 32768, vD + 1024);
    kP += 8192; vP += 128;

    f16x8 qf[2][2];
    const f16* qbase = qws + ((size_t)bh * NN + q0) * DH;
#pragma unroll
    for (int rt = 0; rt < 2; rt++)
#pragma unroll
        for (int ks = 0; ks < 2; ks++)
            qf[rt][ks] = *(const f16x8*)(qbase + (rt * 16 + l15) * DH + ks * 32 + quad * 8);

    int rowOk[2];
#pragma unroll
    for (int rt = 0; rt < 2; rt++)
        rowOk[rt] = mask[(size_t)b * NN + q0 + rt * 16 + l15];

    float pnull[2] = {0.0f, 0.0f};
    if (jh == 0) {
        float pn[2] = {0.f, 0.f};
#pragma unroll
        for (int ks = 0; ks < 2; ks++)
#pragma unroll
            for (int t = 0; t < 8; t++) {
                const float nkt = tanhf(nk[ks * 32 + quad * 8 + t]);
                pn[0] += (float)qf[0][ks][t] * nkt;
                pn[1] += (float)qf[1][ks][t] * nkt;
            }
#pragma unroll
        for (int rt = 0; rt < 2; rt++) {
            pn[rt] += __shfl_xor(pn[rt], 16);
            pn[rt] += __shfl_xor(pn[rt], 32);
            pnull[rt] = rowOk[rt] ? EXP2(pn[rt]) : 1.0f;
        }
    }
    float rowOkf[2];
#pragma unroll
    for (int rt = 0; rt < 2; rt++) {
        rowOkf[rt] = rowOk[rt] ? 1.0f : 0.0f;
        if (!rowOk[rt]) {
            const f16x8 zz = {(f16)0, (f16)0, (f16)0, (f16)0, (f16)0, (f16)0, (f16)0, (f16)0};
            qf[rt][0] = zz; qf[rt][1] = zz;
        }
    }

    f32x4 acc[2][4];
    f32x4 accl[2];
#pragma unroll
    for (int rt = 0; rt < 2; rt++)
#pragma unroll
        for (int reg = 0; reg < 4; reg++) {
            const float pr = __shfl(pnull[rt], quad * 4 + reg, 16);
            accl[rt][reg] = pr;
#pragma unroll
            for (int ds = 0; ds < 4; ds++)
                acc[rt][ds][reg] = pr * nv[ds * 16 + l15];
        }

    const f16x4 vone = {(f16)1, (f16)1, (f16)1, (f16)1};
    const int kxor = l15 & 7;
    const float* cbb = cbias + (size_t)b * MM;

// one tile: BUF = this tile's LDS byte offset, NXT = other buffer's offset,
// JC = this tile's j base, PF = issue prefetch of next tile.
#define ATTN_TILE(BUF, NXT, JC, PF)                                           \
  {                                                                           \
    asm volatile("s_waitcnt vmcnt(0)" ::: "memory");                          \
    __builtin_amdgcn_s_barrier();                                             \
    __builtin_amdgcn_sched_barrier(0);                                        \
    float4 cbv[4];                                                            \
    _Pragma("unroll")                                                         \
    for (int jj = 0; jj < 4; jj++)                                            \
      cbv[jj] = *(const float4*)(cbb + (JC) + jj * 16 + quad * 4);            \
    __builtin_amdgcn_sched_barrier(0);                                        \
    if (PF) {                                                                 \
      gl16(kP,         kD + (NXT));                                           \
      gl16(kP + 1024,  kD + (NXT) + 1024);                                    \
      gl16(vP,         vD + (NXT));                                           \
      gl16(vP + 32768, vD + (NXT) + 1024);                                    \
      kP += 8192; vP += 128;                                                  \
    }                                                                         \
    __builtin_amdgcn_sched_barrier(0);                                        \
    const char* sKb = smem + (BUF);                                           \
    const char* sVb = smem + (BUF) + 8192;                                    \
    f32x4 st[2][4];                                                           \
    _Pragma("unroll")                                                         \
    for (int rt = 0; rt < 2; rt++)                                            \
      _Pragma("unroll")                                                       \
      for (int jj = 0; jj < 4; jj++)                                          \
        _Pragma("unroll")                                                     \
        for (int reg = 0; reg < 4; reg++)                                     \
          st[rt][jj][reg] = cbv[jj][reg] * rowOkf[rt];                        \
    _Pragma("unroll")                                                         \
    for (int ks = 0; ks < 2; ks++) {                                          \
      f16x8 kb[4];                                                            \
      _Pragma("unroll")                                                       \
      for (int jj = 0; jj < 4; jj++)                                          \
        kb[jj] = *(const f16x8*)(sKb + (jj * 16 + l15) * 128                  \
                                     + (((ks * 4 + quad) ^ kxor) << 4));      \
      _Pragma("unroll")                                                       \
      for (int rt = 0; rt < 2; rt++)                                          \
        _Pragma("unroll")                                                     \
        for (int jj = 0; jj < 4; jj++)                                        \
          st[rt][jj] = __builtin_amdgcn_mfma_f32_16x16x32_f16(                \
              kb[jj], qf[rt][ks], st[rt][jj], 0, 0, 0);                       \
    }                                                                         \
    f16x4 pa[2][4];                                                           \
    _Pragma("unroll")                                                         \
    for (int rt = 0; rt < 2; rt++)                                            \
      _Pragma("unroll")                                                       \
      for (int jj = 0; jj < 4; jj++)                                          \
        pa[rt][jj] = pk4(EXP2(st[rt][jj][0]), EXP2(st[rt][jj][1]),            \
                         EXP2(st[rt][jj][2]), EXP2(st[rt][jj][3]));           \
    _Pragma("unroll")                                                         \
    for (int jj = 0; jj < 4; jj++) {                                          \
      f16x4 vb[4];                                                            \
      _Pragma("unroll")                                                       \
      for (int ds = 0; ds < 4; ds++)                                          \
        vb[ds] = *(const f16x4*)(sVb + (ds * 16 + l15) * 128                  \
                                     + (((jj * 2 + (quad >> 1)) ^ kxor) << 4) \
                                     + ((quad & 1) << 3));                    \
      _Pragma("unroll")                                                       \
      for (int rt = 0; rt < 2; rt++) {                                        \
        _Pragma("unroll")                                                     \
        for (int ds = 0; ds < 4; ds++)                                        \
          acc[rt][ds] = __builtin_amdgcn_mfma_f32_16x16x16f16(                \
              pa[rt][jj], vb[ds], acc[rt][ds], 0, 0, 0);                      \
        accl[rt] = __builtin_amdgcn_mfma_f32_16x16x16f16(                     \
            pa[rt][jj], vone, accl[rt], 0, 0, 0);                             \
      }                                                                       \
    }                                                                         \
  }

    int jc = jbeg;
    for (int it = 0; it < 4; it++) {
        ATTN_TILE(0,     16384, jc, 1);        // tiles 0,2,4,6: always prefetch
        jc += 64;
        ATTN_TILE(16384, 0,     jc, it < 3);   // tiles 1,3,5,7: last has none
        jc += 64;
    }
#undef ATTN_TILE

    // epilogue: normalized f16 partials + l
#pragma unroll
    for (int rt = 0; rt < 2; rt++) {
        float inv[4];
#pragma unroll
        for (int reg = 0; reg < 4; reg++)
            inv[reg] = 1.0f / fmaxf(accl[rt][reg], 1e-35f);
#pragma unroll
        for (int ds = 0; ds < 4; ds++)
#pragma unroll
            for (int reg = 0; reg < 4; reg++) {
                const int r = q0 + rt * 16 + quad * 4 + reg;
                Opf[((size_t)jh * 8192 + b * 2048 + r) * 512 + h * 64 + ds * 16 + l15] =
                    (f16)(acc[rt][ds][reg] * inv[reg]);
            }
    }
    if (l15 == 0) {
#pragma unroll
        for (int rt = 0; rt < 2; rt++)
#pragma unroll
            for (int reg = 0; reg < 4; reg++)
                lp[((size_t)jh * 32 + bh) * 2048 + q0 + rt * 16 + quad * 4 + reg] =
                    accl[rt][reg];
    }
}

// ---------------------------------------------------------------------------
// Merge 4 j-partials: O = sum(Ohat_p * l_p) / sum(l_p) -> f16 of16.
// ---------------------------------------------------------------------------
__global__ void merge_k(const f16* __restrict__ Opf, const float* __restrict__ lp,
                        f16* __restrict__ of16)
{
    const int i = blockIdx.x * 256 + threadIdx.x;   // 1,048,576 threads
    const int row = i >> 7;                          // 0..8191
    const int c4  = i & 127;
    const int b = row >> 11, n = row & 2047, h = c4 >> 4;
    float w[4], den = 0.f;
#pragma unroll
    for (int jh = 0; jh < 4; jh++) {
        w[jh] = lp[((size_t)jh * 32 + b * 8 + h) * 2048 + n];
        den += w[jh];
    }
    const float inv = 1.0f / den;
    float v0 = 0, v1 = 0, v2 = 0, v3 = 0;
#pragma unroll
    for (int jh = 0; jh < 4; jh++) {
        f16x4 o = *(const f16x4*)(Opf + ((size_t)jh * 8192 + row) * 512 + c4 * 4);
        v0 += (float)o[0] * w[jh];
        v1 += (float)o[1] * w[jh];
        v2 += (float)o[2] * w[jh];
        v3 += (float)o[3] * w[jh];
    }
    f16x4 r = pk4(v0 * inv, v1 * inv, v2 * inv, v3 * inv);
    *(f16x4*)(of16 + (size_t)row * 512 + c4 * 4) = r;
}

// ---------------------------------------------------------------------------
// Final GEMM: out = O(f16) @ Wo(f16 hi/lo) + bias.  2 MFMAs per sub-tile.
// ---------------------------------------------------------------------------
__launch_bounds__(256)
__global__ void mgemm2(const f16* __restrict__ A, const f16* __restrict__ Bh,
                       const f16* __restrict__ Bl,
                       float* __restrict__ o32, const float* __restrict__ bias,
                       int K)
{
    __shared__ f16 sA[128 * 36];
    __shared__ f16 sBh[64 * 36], sBl[64 * 36];

    const int tid  = threadIdx.x;
    const int wave = tid >> 6, lane = tid & 63;
    const int l15  = lane & 15, quad = lane >> 4;
    const size_t r0 = (size_t)blockIdx.x * 128;
    const int c0 = blockIdx.y * 64;

    const int sr = tid >> 2;
    const int sc = (tid & 3) * 8;

    f32x4 acc[2][4] = {};

    for (int k0 = 0; k0 < K; k0 += 32) {
        uint4 a0 = *(const uint4*)(A + (r0 + sr) * K + k0 + sc);
        uint4 a1 = *(const uint4*)(A + (r0 + 64 + sr) * K + k0 + sc);
        uint4 bh = *(const uint4*)(Bh + (size_t)(c0 + sr) * K + k0 + sc);
        uint4 bl = *(const uint4*)(Bl + (size_t)(c0 + sr) * K + k0 + sc);
        __syncthreads();
        *(uint4*)(sA + sr * 36 + sc)        = a0;
        *(uint4*)(sA + (64 + sr) * 36 + sc) = a1;
        *(uint4*)(sBh + sr * 36 + sc)       = bh;
        *(uint4*)(sBl + sr * 36 + sc)       = bl;
        __syncthreads();

        f16x8 a[2], b_h[4], b_l[4];
#pragma unroll
        for (int rt = 0; rt < 2; rt++)
            a[rt] = *(const f16x8*)(sA + (wave * 32 + rt * 16 + l15) * 36 + quad * 8);
#pragma unroll
        for (int ct = 0; ct < 4; ct++) {
            b_h[ct] = *(const f16x8*)(sBh + (ct * 16 + l15) * 36 + quad * 8);
            b_l[ct] = *(const f16x8*)(sBl + (ct * 16 + l15) * 36 + quad * 8);
        }
#pragma unroll
        for (int rt = 0; rt < 2; rt++)
#pragma unroll
            for (int ct = 0; ct < 4; ct++) {
                acc[rt][ct] = __builtin_amdgcn_mfma_f32_16x16x32_f16(a[rt], b_h[ct], acc[rt][ct], 0, 0, 0);
                acc[rt][ct] = __builtin_amdgcn_mfma_f32_16x16x32_f16(a[rt], b_l[ct], acc[rt][ct], 0, 0, 0);
            }
    }

#pragma unroll
    for (int rt = 0; rt < 2; rt++)
#pragma unroll
        for (int ct = 0; ct < 4; ct++) {
            const int col = c0 + ct * 16 + l15;
            const float bv = bias[col];
#pragma unroll
            for (int reg = 0; reg < 4; reg++) {
                const size_t row = r0 + wave * 32 + rt * 16 + quad * 4 + reg;
                o32[row * 512 + col] = acc[rt][ct][reg] + bv;
            }
        }
}

extern "C" void kernel_launch(void* const* d_in, const int* in_sizes, int n_in,
                              void* d_out, int out_size, void* d_ws, size_t ws_size,
                              hipStream_t stream)
{
    const float* x    = (const float*)d_in[0];
    const float* ctx  = (const float*)d_in[1];
    const int*   mask = (const int*)d_in[2];
    const int*   cmsk = (const int*)d_in[3];
    const float* Wq   = (const float*)d_in[4];
    const float* Wkv  = (const float*)d_in[5];
    const float* Wo   = (const float*)d_in[6];
    const float* bo   = (const float*)d_in[7];
    const float* nk   = (const float*)d_in[8];
    const float* nv   = (const float*)d_in[9];
    float* out = (float*)d_out;

    const size_t S = (size_t)BB * HEADS * NN * DH;  // 4,194,304 elems

    f16* qws = (f16*)d_ws;                  // 8 MB
    f16* kws = qws + S;                     // 8 MB
    f16* vt  = kws + S;                     // 8 MB
    f16* wq16  = vt + S;                    // 0.5 MB
    f16* wkv16 = wq16 + 512 * 512;          // 1 MB
    f16* woh = wkv16 + 512 * 1024;          // 0.5 MB
    f16* wol = woh + 512 * 512;             // 0.5 MB
    float* lp = (float*)(wol + 512 * 512);  // 1 MB
    f16* Opf = (f16*)(lp + 4 * 32 * 2048);  // 32 MB
    f16* of16 = qws;                        // alias (qws dead after attn_k)
    // xf/cf live in the Opf region (dead until attn_k); cbias after Opf.
    f16* xf16 = Opf;                        // 8 MB
    f16* cf16 = xf16 + (size_t)BB * NN * 512;  // 8 MB
    float* cbias = (float*)(Opf + (size_t)4 * 8192 * 512);  // 32 KB after Opf

    wprep_k<<<516, 256, 0, stream>>>(Wq, Wkv, Wo, cmsk, wq16, wkv16, woh, wol, cbias);
    xprep_k<<<4096, 256, 0, stream>>>(x, ctx, xf16, cf16);
    proj_k<<<dim3(64, 12), 256, 0, stream>>>(xf16, cf16, wq16, wkv16, qws, kws, vt);
    attn_k<<<dim3(32, 16, 4), 256, 0, stream>>>(qws, kws, vt, mask, cbias, nk, nv, Opf, lp);
    merge_k<<<4096, 256, 0, stream>>>(Opf, lp, of16);
    mgemm2<<<dim3(64, 8), 256, 0, stream>>>(of16, woh, wol, out, bo, 512);
}

// Round 4
// 199.216 us; speedup vs baseline: 1.0329x; 1.0329x over previous
//
#include <hip/hip_runtime.h>
#include <math.h>

#define BB 4
#define NN 2048
#define MM 2048
#define HEADS 8
#define DH 64

typedef _Float16 f16;
typedef _Float16 f16x4 __attribute__((ext_vector_type(4)));
typedef _Float16 f16x8 __attribute__((ext_vector_type(8)));
typedef float f32x4 __attribute__((ext_vector_type(4)));
typedef unsigned short ushort;

#define LOG2E 1.44269504088896f
#define QSCALE (0.125f * LOG2E)

#if __has_builtin(__builtin_amdgcn_exp2f)
#define EXP2(x) __builtin_amdgcn_exp2f(x)
#else
#define EXP2(x) exp2f(x)
#endif

__device__ __forceinline__ f16x4 pk4(float a, float b, float c, float d) {
#if __has_builtin(__builtin_amdgcn_cvt_pkrtz)
    auto t0 = __builtin_amdgcn_cvt_pkrtz(a, b);
    auto t1 = __builtin_amdgcn_cvt_pkrtz(c, d);
    f16x4 r;
    r[0] = t0[0]; r[1] = t0[1]; r[2] = t1[0]; r[3] = t1[1];
    return r;
#else
    f16x4 r = {(f16)a, (f16)b, (f16)c, (f16)d};
    return r;
#endif
}

// async global->LDS, 16B per lane, dest = wave-uniform base + lane*16
__device__ __forceinline__ void gl16(const void* g, void* l) {
    __builtin_amdgcn_global_load_lds(
        (const __attribute__((address_space(1))) unsigned int*)g,
        (__attribute__((address_space(3))) unsigned int*)l, 16, 0, 0);
}

// ---------------------------------------------------------------------------
// Fused weight prep: Wq->[N][K]f16, Wkv->[N][K]f16, Wo->[N][K] f16 hi/lo.
// 512 blocks: [0,128) Wq, [128,384) Wkv, [384,512) Wo.
// ---------------------------------------------------------------------------
__global__ void wprep_k(const float* __restrict__ Wq, const float* __restrict__ Wkv,
                        const float* __restrict__ Wo,
                        f16* __restrict__ wq16, f16* __restrict__ wkv16,
                        f16* __restrict__ woh, f16* __restrict__ wol)
{
    __shared__ f16 S0[64 * 36], S1[64 * 36];
    const int tid = threadIdx.x;
    const int bid = blockIdx.x;
    const int K = 512;
    const float* W; int N; f16* T16; f16 *Th, *Tl; int id;
    if (bid < 128)      { W = Wq;  N = 512;  T16 = wq16;  Th = 0; Tl = 0; id = bid; }
    else if (bid < 384) { W = Wkv; N = 1024; T16 = wkv16; Th = 0; Tl = 0; id = bid - 128; }
    else                { W = Wo;  N = 512;  T16 = 0; Th = woh; Tl = wol; id = bid - 384; }
    const int k0 = (id & 15) * 32, n0 = (id >> 4) * 64;
    const int kr = tid >> 3, nc = (tid & 7) * 8;
    float4 v0 = *(const float4*)(W + (size_t)(k0 + kr) * N + n0 + nc);
    float4 v1 = *(const float4*)(W + (size_t)(k0 + kr) * N + n0 + nc + 4);
    float e[8] = {v0.x, v0.y, v0.z, v0.w, v1.x, v1.y, v1.z, v1.w};
    const int n = tid >> 2, kc = (tid & 3) * 8;
    if (T16) {
#pragma unroll
        for (int j = 0; j < 8; j++) S0[(nc + j) * 36 + kr] = (f16)e[j];
        __syncthreads();
        *(uint4*)(T16 + (size_t)(n0 + n) * K + k0 + kc) = *(const uint4*)(S0 + n * 36 + kc);
    } else {
#pragma unroll
        for (int j = 0; j < 8; j++) {
            f16 h = (f16)e[j];
            S0[(nc + j) * 36 + kr] = h;
            S1[(nc + j) * 36 + kr] = (f16)(e[j] - (float)h);
        }
        __syncthreads();
        *(uint4*)(Th + (size_t)(n0 + n) * K + k0 + kc) = *(const uint4*)(S0 + n * 36 + kc);
        *(uint4*)(Tl + (size_t)(n0 + n) * K + k0 + kc) = *(const uint4*)(S1 + n * 36 + kc);
    }
}

// ---------------------------------------------------------------------------
// x/ctx f32 -> f16 (outputs live in the then-dead Opf region).
// ---------------------------------------------------------------------------
__global__ void xprep_k(const float* __restrict__ x, const float* __restrict__ ctx,
                        f16* __restrict__ xf, f16* __restrict__ cf)
{
    const size_t S = (size_t)BB * NN * 512;
    const size_t i = ((size_t)blockIdx.x * 256 + threadIdx.x) * 8;
    const float* src = (i < S) ? x + i : ctx + (i - S);
    f16* dst         = (i < S) ? xf + i : cf + (i - S);
    float4 v0 = *(const float4*)(src);
    float4 v1 = *(const float4*)(src + 4);
    f16x8 o;
    o[0] = (f16)v0.x; o[1] = (f16)v0.y; o[2] = (f16)v0.z; o[3] = (f16)v0.w;
    o[4] = (f16)v1.x; o[5] = (f16)v1.y; o[6] = (f16)v1.z; o[7] = (f16)v1.w;
    *(f16x8*)dst = o;
}

// ---------------------------------------------------------------------------
// Fused projections v2: gl16 DMA staging, linear dbuf LDS (2x16KB), one
// barrier per k-step. Source-side XOR swizzle chunk ^= ((row>>1)&3) keeps
// ds_read_b128 frag reads at 2-way (free). 128x128 tiles, grid (64,12).
// by 0..3: Q = tanh(x@Wq)*QSCALE -> qws; by 4..11: K=tanh->kws / V->vt[d][m]
// ---------------------------------------------------------------------------
__launch_bounds__(256, 3)
__global__ void proj_k(const f16* __restrict__ xf, const f16* __restrict__ cf,
                       const f16* __restrict__ wq16, const f16* __restrict__ wkv16,
                       f16* __restrict__ qws, f16* __restrict__ kws, f16* __restrict__ vt)
{
    __shared__ __align__(16) char smem[32768];   // 2 x [A:8KB | B:8KB]

    const int tid  = threadIdx.x;
    const int wave = tid >> 6, lane = tid & 63;
    const int l15  = lane & 15, quad = lane >> 4;
    const int by = blockIdx.y;
    const int isQ = (by < 4);
    const f16* A16 = isQ ? xf : cf;
    const f16* Bt  = isQ ? wq16 : wkv16;
    const int c0 = (isQ ? by : by - 4) * 128;
    const size_t r0 = (size_t)blockIdx.x * 128;
    const int K = 512;

    // DMA staging geometry: chunk idx = wave*128 + i*64 + lane, i in {0,1};
    // row = idx>>2 (0..127), chunk = lane&3, src chunk ^= ((row>>1)&3)
    // which reduces to (lane>>3)&3.
    const int row0 = wave * 32 + (lane >> 2);          // i=0 row
    const int swc  = (lane & 3) ^ ((lane >> 3) & 3);   // source chunk (both i)
    const char* aP0 = (const char*)(A16 + (r0 + row0) * K)       + swc * 16;
    const char* aP1 = (const char*)(A16 + (r0 + row0 + 16) * K)  + swc * 16;
    const char* bP0 = (const char*)(Bt + (size_t)(c0 + row0) * K)      + swc * 16;
    const char* bP1 = (const char*)(Bt + (size_t)(c0 + row0 + 16) * K) + swc * 16;
    char* aD = smem + wave * 2048;           // + i*1024
    char* bD = smem + 8192 + wave * 2048;

    // prologue: stage k0=0 into buf0
    gl16(aP0, aD); gl16(aP1, aD + 1024);
    gl16(bP0, bD); gl16(bP1, bD + 1024);
    aP0 += 64; aP1 += 64; bP0 += 64; bP1 += 64;

    // frag-read swizzle: chunk = quad ^ ((row>>1)&3) = quad ^ ((l15>>1)&3)
    const int fsw = ((quad ^ ((l15 >> 1) & 3)) << 4);
    const int aoff0 = (wave * 32 + l15) * 64 + fsw;          // rt=0 row
    const int aoff1 = (wave * 32 + 16 + l15) * 64 + fsw;     // rt=1 row

    f32x4 acc[2][8] = {};
    __syncthreads();

    int buf = 0;
    for (int t = 0; t < 16; t++) {
        const int nb = (buf ^ 1) * 16384;
        if (t < 15) {
            gl16(aP0, aD + nb); gl16(aP1, aD + nb + 1024);
            gl16(bP0, bD + nb); gl16(bP1, bD + nb + 1024);
            aP0 += 64; aP1 += 64; bP0 += 64; bP1 += 64;
        }
        const char* sA = smem + buf * 16384;
        const char* sB = sA + 8192;

        f16x8 a[2];
        a[0] = *(const f16x8*)(sA + aoff0);
        a[1] = *(const f16x8*)(sA + aoff1);
#pragma unroll
        for (int half = 0; half < 2; half++) {
            f16x8 b[4];
#pragma unroll
            for (int c = 0; c < 4; c++)
                b[c] = *(const f16x8*)(sB + ((half * 4 + c) * 16 + l15) * 64 + fsw);
#pragma unroll
            for (int rt = 0; rt < 2; rt++)
#pragma unroll
                for (int c = 0; c < 4; c++)
                    acc[rt][half * 4 + c] = __builtin_amdgcn_mfma_f32_16x16x32_f16(
                        a[rt], b[c], acc[rt][half * 4 + c], 0, 0, 0);
        }
        __syncthreads();
        buf ^= 1;
    }

    const int b    = (int)(r0 >> 11);
    const int rloc = ((int)(r0 & 2047)) + wave * 32;

#pragma unroll
    for (int rt = 0; rt < 2; rt++)
#pragma unroll
        for (int ct = 0; ct < 8; ct++) {
            const int col = c0 + ct * 16 + l15;
            if (isQ || col < 512) {
                const int h = (col >> 6) & 7;
                const int d = col & 63;
                f16* dst = isQ ? qws : kws;
                const float sc = isQ ? QSCALE : 1.0f;
#pragma unroll
                for (int reg = 0; reg < 4; reg++) {
                    const int nn = rloc + rt * 16 + quad * 4 + reg;
                    dst[(((size_t)b * 8 + h) * 2048 + nn) * 64 + d] =
                        (f16)(tanhf(acc[rt][ct][reg]) * sc);
                }
            } else {
                const int c = col - 512;
                const int h = c >> 6;
                const int d = c & 63;
                const int m0 = rloc + rt * 16 + quad * 4;
                f16x4 pk;
#pragma unroll
                for (int reg = 0; reg < 4; reg++) pk[reg] = (f16)acc[rt][ct][reg];
                *(f16x4*)(vt + (((size_t)b * 8 + h) * 64 + d) * 2048 + m0) = pk;
            }
        }
}

// ---------------------------------------------------------------------------
// MFMA fp16 flash attention (v9, proven 58.3us): gl16 DMA staging into a
// linear double-buffered LDS with one __syncthreads per 64-j tile; mask
// loads + prefetch issued before compute so their latency hides under it.
// Source-side XOR swizzle (chunk ^ row&7) <-> matching read-side XOR.
// ---------------------------------------------------------------------------
__launch_bounds__(256, 4)
__global__ void attn_k(const f16* __restrict__ qws, const f16* __restrict__ kws,
                       const f16* __restrict__ vtws,
                       const int* __restrict__ mask, const int* __restrict__ cmask,
                       const float* __restrict__ nk, const float* __restrict__ nv,
                       f16* __restrict__ Opf, float* __restrict__ lp)
{
    __shared__ __align__(16) char smem[32768];   // [2][ K:8192 | V:8192 ]

    const int tid  = threadIdx.x;
    const int wave = tid >> 6, lane = tid & 63;
    const int l15  = lane & 15, quad = lane >> 4;
    const int bh = blockIdx.x, b = bh >> 3, h = bh & 7;
    const int q0 = blockIdx.y * 128 + wave * 32;
    const int jh = blockIdx.z;
    const int jbeg = jh << 9, jend = jbeg + 512;

    const f16* kg0 = kws + (size_t)bh * MM * DH;
    const f16* vg0 = vtws + (size_t)bh * DH * MM;

    const int lrow = lane >> 3;
    const int lsw  = ((lane & 7) ^ lrow) << 4;
    const char* kP = (const char*)kg0 + (size_t)(jbeg + wave * 16 + lrow) * 128 + lsw;
    const char* vP = (const char*)vg0 + (size_t)(wave * 16 + lrow) * 4096
                   + (size_t)jbeg * 2 + lsw;
    char* kD = smem + wave * 2048;
    char* vD = smem + 8192 + wave * 2048;

    gl16(kP,         kD);
    gl16(kP + 1024,  kD + 1024);
    gl16(vP,         vD);
    gl16(vP + 32768, vD + 1024);
    kP += 8192; vP += 128;

    f16x8 qf[2][2];
    const f16* qbase = qws + ((size_t)bh * NN + q0) * DH;
#pragma unroll
    for (int rt = 0; rt < 2; rt++)
#pragma unroll
        for (int ks = 0; ks < 2; ks++)
            qf[rt][ks] = *(const f16x8*)(qbase + (rt * 16 + l15) * DH + ks * 32 + quad * 8);

    int rowOk[2];
#pragma unroll
    for (int rt = 0; rt < 2; rt++)
        rowOk[rt] = mask[(size_t)b * NN + q0 + rt * 16 + l15];

    float pnull[2] = {0.0f, 0.0f};
    if (jh == 0) {
        float pn[2] = {0.f, 0.f};
#pragma unroll
        for (int ks = 0; ks < 2; ks++)
#pragma unroll
            for (int t = 0; t < 8; t++) {
                const float nkt = tanhf(nk[ks * 32 + quad * 8 + t]);
                pn[0] += (float)qf[0][ks][t] * nkt;
                pn[1] += (float)qf[1][ks][t] * nkt;
            }
#pragma unroll
        for (int rt = 0; rt < 2; rt++) {
            pn[rt] += __shfl_xor(pn[rt], 16);
            pn[rt] += __shfl_xor(pn[rt], 32);
            pnull[rt] = rowOk[rt] ? EXP2(pn[rt]) : 1.0f;
        }
    }
    float negsel[2];
#pragma unroll
    for (int rt = 0; rt < 2; rt++) {
        negsel[rt] = rowOk[rt] ? -1.0e30f : 0.0f;
        if (!rowOk[rt]) {
            const f16x8 zz = {(f16)0, (f16)0, (f16)0, (f16)0, (f16)0, (f16)0, (f16)0, (f16)0};
            qf[rt][0] = zz; qf[rt][1] = zz;
        }
    }

    f32x4 acc[2][4];
    f32x4 accl[2];
#pragma unroll
    for (int rt = 0; rt < 2; rt++)
#pragma unroll
        for (int reg = 0; reg < 4; reg++) {
            const float pr = __shfl(pnull[rt], quad * 4 + reg, 16);
            accl[rt][reg] = pr;
#pragma unroll
            for (int ds = 0; ds < 4; ds++)
                acc[rt][ds][reg] = pr * nv[ds * 16 + l15];
        }

    const f16x4 vone = {(f16)1, (f16)1, (f16)1, (f16)1};
    const int kxor = l15 & 7;

    __syncthreads();

    int buf = 0;
    for (int jc = jbeg; jc < jend; jc += 64) {
        int4 cmv[4];
#pragma unroll
        for (int jj = 0; jj < 4; jj++)
            cmv[jj] = *(const int4*)(cmask + (size_t)b * MM + jc + jj * 16 + quad * 4);

        if (jc + 64 < jend) {
            const int bo = (buf ^ 1) << 14;
            gl16(kP,         kD + bo);
            gl16(kP + 1024,  kD + bo + 1024);
            gl16(vP,         vD + bo);
            gl16(vP + 32768, vD + bo + 1024);
            kP += 8192; vP += 128;
        }

        const char* sKb = smem + (buf << 14);
        const char* sVb = sKb + 8192;

        f32x4 st[2][4];
#pragma unroll
        for (int rt = 0; rt < 2; rt++)
#pragma unroll
            for (int jj = 0; jj < 4; jj++) {
                st[rt][jj][0] = cmv[jj].x ? 0.0f : negsel[rt];
                st[rt][jj][1] = cmv[jj].y ? 0.0f : negsel[rt];
                st[rt][jj][2] = cmv[jj].z ? 0.0f : negsel[rt];
                st[rt][jj][3] = cmv[jj].w ? 0.0f : negsel[rt];
            }

#pragma unroll
        for (int ks = 0; ks < 2; ks++) {
            f16x8 kb[4];
#pragma unroll
            for (int jj = 0; jj < 4; jj++)
                kb[jj] = *(const f16x8*)(sKb + (jj * 16 + l15) * 128
                                             + (((ks * 4 + quad) ^ kxor) << 4));
#pragma unroll
            for (int rt = 0; rt < 2; rt++)
#pragma unroll
                for (int jj = 0; jj < 4; jj++)
                    st[rt][jj] = __builtin_amdgcn_mfma_f32_16x16x32_f16(
                        kb[jj], qf[rt][ks], st[rt][jj], 0, 0, 0);
        }

        f16x4 pa[2][4];
#pragma unroll
        for (int rt = 0; rt < 2; rt++)
#pragma unroll
            for (int jj = 0; jj < 4; jj++)
                pa[rt][jj] = pk4(EXP2(st[rt][jj][0]), EXP2(st[rt][jj][1]),
                                 EXP2(st[rt][jj][2]), EXP2(st[rt][jj][3]));

#pragma unroll
        for (int jj = 0; jj < 4; jj++) {
            f16x4 vb[4];
#pragma unroll
            for (int ds = 0; ds < 4; ds++)
                vb[ds] = *(const f16x4*)(sVb + (ds * 16 + l15) * 128
                                             + (((jj * 2 + (quad >> 1)) ^ kxor) << 4)
                                             + ((quad & 1) << 3));
#pragma unroll
            for (int rt = 0; rt < 2; rt++) {
#pragma unroll
                for (int ds = 0; ds < 4; ds++)
                    acc[rt][ds] = __builtin_amdgcn_mfma_f32_16x16x16f16(
                        pa[rt][jj], vb[ds], acc[rt][ds], 0, 0, 0);
                accl[rt] = __builtin_amdgcn_mfma_f32_16x16x16f16(
                    pa[rt][jj], vone, accl[rt], 0, 0, 0);
            }
        }

        __syncthreads();
        buf ^= 1;
    }

    // epilogue: normalized f16 partials + l
#pragma unroll
    for (int rt = 0; rt < 2; rt++) {
        float inv[4];
#pragma unroll
        for (int reg = 0; reg < 4; reg++)
            inv[reg] = 1.0f / fmaxf(accl[rt][reg], 1e-35f);
#pragma unroll
        for (int ds = 0; ds < 4; ds++)
#pragma unroll
            for (int reg = 0; reg < 4; reg++) {
                const int r = q0 + rt * 16 + quad * 4 + reg;
                Opf[((size_t)jh * 8192 + b * 2048 + r) * 512 + h * 64 + ds * 16 + l15] =
                    (f16)(acc[rt][ds][reg] * inv[reg]);
            }
    }
    if (l15 == 0) {
#pragma unroll
        for (int rt = 0; rt < 2; rt++)
#pragma unroll
            for (int reg = 0; reg < 4; reg++)
                lp[((size_t)jh * 32 + bh) * 2048 + q0 + rt * 16 + quad * 4 + reg] =
                    accl[rt][reg];
    }
}

// ---------------------------------------------------------------------------
// Merge 4 j-partials: O = sum(Ohat_p * l_p) / sum(l_p) -> f16 of16.
// ---------------------------------------------------------------------------
__global__ void merge_k(const f16* __restrict__ Opf, const float* __restrict__ lp,
                        f16* __restrict__ of16)
{
    const int i = blockIdx.x * 256 + threadIdx.x;   // 1,048,576 threads
    const int row = i >> 7;                          // 0..8191
    const int c4  = i & 127;
    const int b = row >> 11, n = row & 2047, h = c4 >> 4;
    float w[4], den = 0.f;
#pragma unroll
    for (int jh = 0; jh < 4; jh++) {
        w[jh] = lp[((size_t)jh * 32 + b * 8 + h) * 2048 + n];
        den += w[jh];
    }
    const float inv = 1.0f / den;
    float v0 = 0, v1 = 0, v2 = 0, v3 = 0;
#pragma unroll
    for (int jh = 0; jh < 4; jh++) {
        f16x4 o = *(const f16x4*)(Opf + ((size_t)jh * 8192 + row) * 512 + c4 * 4);
        v0 += (float)o[0] * w[jh];
        v1 += (float)o[1] * w[jh];
        v2 += (float)o[2] * w[jh];
        v3 += (float)o[3] * w[jh];
    }
    f16x4 r = pk4(v0 * inv, v1 * inv, v2 * inv, v3 * inv);
    *(f16x4*)(of16 + (size_t)row * 512 + c4 * 4) = r;
}

// ---------------------------------------------------------------------------
// Final GEMM v2: out = O(f16) @ Wo(f16 hi/lo) + bias. 128x128 tiles,
// gl16 DMA staging into linear dbuf LDS (2x24KB), one barrier per k-step,
// 32 MFMA per k-step (4x the old density). grid (64,4).
// ---------------------------------------------------------------------------
__launch_bounds__(256, 3)
__global__ void mgemm2(const f16* __restrict__ A, const f16* __restrict__ Bh,
                       const f16* __restrict__ Bl,
                       float* __restrict__ o32, const float* __restrict__ bias,
                       int K)
{
    __shared__ __align__(16) char smem[49152];   // 2 x [A:8KB | Bh:8KB | Bl:8KB]

    const int tid  = threadIdx.x;
    const int wave = tid >> 6, lane = tid & 63;
    const int l15  = lane & 15, quad = lane >> 4;
    const size_t r0 = (size_t)blockIdx.x * 128;
    const int c0 = blockIdx.y * 128;

    // DMA staging geometry (same derivation as proj_k)
    const int row0 = wave * 32 + (lane >> 2);
    const int swc  = (lane & 3) ^ ((lane >> 3) & 3);
    const char* aP0 = (const char*)(A + (r0 + row0) * K)       + swc * 16;
    const char* aP1 = (const char*)(A + (r0 + row0 + 16) * K)  + swc * 16;
    const char* hP0 = (const char*)(Bh + (size_t)(c0 + row0) * K)      + swc * 16;
    const char* hP1 = (const char*)(Bh + (size_t)(c0 + row0 + 16) * K) + swc * 16;
    const char* lP0 = (const char*)(Bl + (size_t)(c0 + row0) * K)      + swc * 16;
    const char* lP1 = (const char*)(Bl + (size_t)(c0 + row0 + 16) * K) + swc * 16;
    char* aD = smem + wave * 2048;
    char* hD = smem + 8192 + wave * 2048;
    char* lD = smem + 16384 + wave * 2048;

    gl16(aP0, aD); gl16(aP1, aD + 1024);
    gl16(hP0, hD); gl16(hP1, hD + 1024);
    gl16(lP0, lD); gl16(lP1, lD + 1024);
    aP0 += 64; aP1 += 64; hP0 += 64; hP1 += 64; lP0 += 64; lP1 += 64;

    const int fsw = ((quad ^ ((l15 >> 1) & 3)) << 4);
    const int aoff0 = (wave * 32 + l15) * 64 + fsw;
    const int aoff1 = (wave * 32 + 16 + l15) * 64 + fsw;

    f32x4 acc[2][8] = {};
    __syncthreads();

    int buf = 0;
    const int NT = K / 32;
    for (int t = 0; t < NT; t++) {
        const int nb = (buf ^ 1) * 24576;
        if (t < NT - 1) {
            gl16(aP0, aD + nb); gl16(aP1, aD + nb + 1024);
            gl16(hP0, hD + nb); gl16(hP1, hD + nb + 1024);
            gl16(lP0, lD + nb); gl16(lP1, lD + nb + 1024);
            aP0 += 64; aP1 += 64; hP0 += 64; hP1 += 64; lP0 += 64; lP1 += 64;
        }
        const char* sA = smem + buf * 24576;
        const char* sH = sA + 8192;
        const char* sL = sA + 16384;

        f16x8 a[2];
        a[0] = *(const f16x8*)(sA + aoff0);
        a[1] = *(const f16x8*)(sA + aoff1);
#pragma unroll
        for (int half = 0; half < 2; half++) {
#pragma unroll
            for (int c = 0; c < 4; c++) {
                const int ct = half * 4 + c;
                const int boff = (ct * 16 + l15) * 64 + fsw;
                f16x8 bh = *(const f16x8*)(sH + boff);
                f16x8 bl = *(const f16x8*)(sL + boff);
#pragma unroll
                for (int rt = 0; rt < 2; rt++) {
                    acc[rt][ct] = __builtin_amdgcn_mfma_f32_16x16x32_f16(
                        a[rt], bh, acc[rt][ct], 0, 0, 0);
                    acc[rt][ct] = __builtin_amdgcn_mfma_f32_16x16x32_f16(
                        a[rt], bl, acc[rt][ct], 0, 0, 0);
                }
            }
        }
        __syncthreads();
        buf ^= 1;
    }

#pragma unroll
    for (int rt = 0; rt < 2; rt++)
#pragma unroll
        for (int ct = 0; ct < 8; ct++) {
            const int col = c0 + ct * 16 + l15;
            const float bv = bias[col];
#pragma unroll
            for (int reg = 0; reg < 4; reg++) {
                const size_t row = r0 + wave * 32 + rt * 16 + quad * 4 + reg;
                o32[row * 512 + col] = acc[rt][ct][reg] + bv;
            }
        }
}

extern "C" void kernel_launch(void* const* d_in, const int* in_sizes, int n_in,
                              void* d_out, int out_size, void* d_ws, size_t ws_size,
                              hipStream_t stream)
{
    const float* x    = (const float*)d_in[0];
    const float* ctx  = (const float*)d_in[1];
    const int*   mask = (const int*)d_in[2];
    const int*   cmsk = (const int*)d_in[3];
    const float* Wq   = (const float*)d_in[4];
    const float* Wkv  = (const float*)d_in[5];
    const float* Wo   = (const float*)d_in[6];
    const float* bo   = (const float*)d_in[7];
    const float* nk   = (const float*)d_in[8];
    const float* nv   = (const float*)d_in[9];
    float* out = (float*)d_out;

    const size_t S = (size_t)BB * HEADS * NN * DH;  // 4,194,304 elems

    f16* qws = (f16*)d_ws;                  // 8 MB
    f16* kws = qws + S;                     // 8 MB
    f16* vt  = kws + S;                     // 8 MB
    f16* wq16  = vt + S;                    // 0.5 MB
    f16* wkv16 = wq16 + 512 * 512;          // 1 MB
    f16* woh = wkv16 + 512 * 1024;          // 0.5 MB
    f16* wol = woh + 512 * 512;             // 0.5 MB
    float* lp = (float*)(wol + 512 * 512);  // 1 MB
    f16* Opf = (f16*)(lp + 4 * 32 * 2048);  // 32 MB
    f16* of16 = qws;                        // alias (qws dead after attn_k)
    // xf/cf live in the Opf region (dead until attn_k)
    f16* xf16 = Opf;                        // 8 MB
    f16* cf16 = xf16 + (size_t)BB * NN * 512;  // 8 MB

    wprep_k<<<512, 256, 0, stream>>>(Wq, Wkv, Wo, wq16, wkv16, woh, wol);
    xprep_k<<<4096, 256, 0, stream>>>(x, ctx, xf16, cf16);
    proj_k<<<dim3(64, 12), 256, 0, stream>>>(xf16, cf16, wq16, wkv16, qws, kws, vt);
    attn_k<<<dim3(32, 16, 4), 256, 0, stream>>>(qws, kws, vt, mask, cmsk, nk, nv, Opf, lp);
    merge_k<<<4096, 256, 0, stream>>>(Opf, lp, of16);
    mgemm2<<<dim3(64, 4), 256, 0, stream>>>(of16, woh, wol, out, bo, 512);
}

// Round 5
// 190.138 us; speedup vs baseline: 1.0822x; 1.0477x over previous
//
#include <hip/hip_runtime.h>
#include <math.h>

#define BB 4
#define NN 2048
#define MM 2048
#define HEADS 8
#define DH 64

typedef _Float16 f16;
typedef _Float16 f16x4 __attribute__((ext_vector_type(4)));
typedef _Float16 f16x8 __attribute__((ext_vector_type(8)));
typedef float f32x4 __attribute__((ext_vector_type(4)));
typedef unsigned short ushort;

#define LOG2E 1.44269504088896f
#define QSCALE (0.125f * LOG2E)

#if __has_builtin(__builtin_amdgcn_exp2f)
#define EXP2(x) __builtin_amdgcn_exp2f(x)
#else
#define EXP2(x) exp2f(x)
#endif

__device__ __forceinline__ f16x4 pk4(float a, float b, float c, float d) {
#if __has_builtin(__builtin_amdgcn_cvt_pkrtz)
    auto t0 = __builtin_amdgcn_cvt_pkrtz(a, b);
    auto t1 = __builtin_amdgcn_cvt_pkrtz(c, d);
    f16x4 r;
    r[0] = t0[0]; r[1] = t0[1]; r[2] = t1[0]; r[3] = t1[1];
    return r;
#else
    f16x4 r = {(f16)a, (f16)b, (f16)c, (f16)d};
    return r;
#endif
}

// async global->LDS, 16B per lane, dest = wave-uniform base + lane*16
__device__ __forceinline__ void gl16(const void* g, void* l) {
    __builtin_amdgcn_global_load_lds(
        (const __attribute__((address_space(1))) unsigned int*)g,
        (__attribute__((address_space(3))) unsigned int*)l, 16, 0, 0);
}

// ---------------------------------------------------------------------------
// Fused weight prep: Wq->[N][K]f16, Wkv->[N][K]f16, Wo->[N][K] f16 hi/lo.
// 512 blocks: [0,128) Wq, [128,384) Wkv, [384,512) Wo.
// ---------------------------------------------------------------------------
__global__ void wprep_k(const float* __restrict__ Wq, const float* __restrict__ Wkv,
                        const float* __restrict__ Wo,
                        f16* __restrict__ wq16, f16* __restrict__ wkv16,
                        f16* __restrict__ woh, f16* __restrict__ wol)
{
    __shared__ f16 S0[64 * 36], S1[64 * 36];
    const int tid = threadIdx.x;
    const int bid = blockIdx.x;
    const int K = 512;
    const float* W; int N; f16* T16; f16 *Th, *Tl; int id;
    if (bid < 128)      { W = Wq;  N = 512;  T16 = wq16;  Th = 0; Tl = 0; id = bid; }
    else if (bid < 384) { W = Wkv; N = 1024; T16 = wkv16; Th = 0; Tl = 0; id = bid - 128; }
    else                { W = Wo;  N = 512;  T16 = 0; Th = woh; Tl = wol; id = bid - 384; }
    const int k0 = (id & 15) * 32, n0 = (id >> 4) * 64;
    const int kr = tid >> 3, nc = (tid & 7) * 8;
    float4 v0 = *(const float4*)(W + (size_t)(k0 + kr) * N + n0 + nc);
    float4 v1 = *(const float4*)(W + (size_t)(k0 + kr) * N + n0 + nc + 4);
    float e[8] = {v0.x, v0.y, v0.z, v0.w, v1.x, v1.y, v1.z, v1.w};
    const int n = tid >> 2, kc = (tid & 3) * 8;
    if (T16) {
#pragma unroll
        for (int j = 0; j < 8; j++) S0[(nc + j) * 36 + kr] = (f16)e[j];
        __syncthreads();
        *(uint4*)(T16 + (size_t)(n0 + n) * K + k0 + kc) = *(const uint4*)(S0 + n * 36 + kc);
    } else {
#pragma unroll
        for (int j = 0; j < 8; j++) {
            f16 h = (f16)e[j];
            S0[(nc + j) * 36 + kr] = h;
            S1[(nc + j) * 36 + kr] = (f16)(e[j] - (float)h);
        }
        __syncthreads();
        *(uint4*)(Th + (size_t)(n0 + n) * K + k0 + kc) = *(const uint4*)(S0 + n * 36 + kc);
        *(uint4*)(Tl + (size_t)(n0 + n) * K + k0 + kc) = *(const uint4*)(S1 + n * 36 + kc);
    }
}

// ---------------------------------------------------------------------------
// Fused projections v3: stages f32 x/ctx DIRECTLY via gl16 (xprep deleted).
// LDS/buf = A-f32 16KB (128 rows x 128B, chunk^=(row&7) swizzle) + B-f16 8KB
// (chunk^=((row>>1)&3)). 48KB total -> 3 blocks/CU = grid 768/256 exactly.
// A frags: 2x ds_read_b128 (f32) + 8 RTE cvt -> f16x8 (same rounding as the
// old xprep path). One barrier per k-step, DMA prefetch of next k-step.
// by 0..3: Q = tanh(x@Wq)*QSCALE -> qws; by 4..11: K=tanh->kws / V->vt[d][m]
// ---------------------------------------------------------------------------
__launch_bounds__(256, 3)
__global__ void proj_k(const float* __restrict__ x, const float* __restrict__ ctx,
                       const f16* __restrict__ wq16, const f16* __restrict__ wkv16,
                       f16* __restrict__ qws, f16* __restrict__ kws, f16* __restrict__ vt)
{
    __shared__ __align__(16) char smem[49152];   // 2 x [A-f32:16KB | B:8KB]

    const int tid  = threadIdx.x;
    const int wave = tid >> 6, lane = tid & 63;
    const int l15  = lane & 15, quad = lane >> 4;
    const int by = blockIdx.y;
    const int isQ = (by < 4);
    const float* A32 = isQ ? x : ctx;
    const f16* Bt  = isQ ? wq16 : wkv16;
    const int c0 = (isQ ? by : by - 4) * 128;
    const size_t r0 = (size_t)blockIdx.x * 128;
    const int K = 512;

    // A staging: 4 gl16/wave; gl16 i covers rows wave*32+i*8+(lane>>3),
    // 16B chunk (lane&7), source chunk ^= (row&7) = (lane>>3).
    const int alr = lane >> 3;
    const int asw = (lane & 7) ^ alr;
    const char* aP = (const char*)(A32 + (r0 + wave * 32 + alr) * K) + asw * 16;
    // B staging: 2 gl16/wave; gl16 i covers rows wave*32+i*16+(lane>>2),
    // chunk (lane&3), source chunk ^= ((row>>1)&3) = ((lane>>3)&3).
    const int blr = lane >> 2;
    const int bsw = (lane & 3) ^ ((lane >> 3) & 3);
    const char* bP = (const char*)(Bt + (size_t)(c0 + wave * 32 + blr) * K) + bsw * 16;
    char* aD = smem + wave * 4096;
    char* bD = smem + 16384 + wave * 2048;

    // prologue: stage k-step 0 into buf0
    gl16(aP,          aD);
    gl16(aP + 16384,  aD + 1024);   // +8 rows  (8*512*4  B)
    gl16(aP + 32768,  aD + 2048);   // +16 rows
    gl16(aP + 49152,  aD + 3072);   // +24 rows
    gl16(bP,          bD);
    gl16(bP + 16384,  bD + 1024);   // +16 rows (16*512*2 B)
    aP += 128; bP += 64;

    // frag-read swizzles
    const int ax  = l15 & 7;                              // A chunk xor
    const int fsw = ((quad ^ ((l15 >> 1) & 3)) << 4);     // B byte xor
    const int arow0 = (wave * 32 + l15) * 128;            // rt=0 A row byte
    const int ac0 = (((2 * quad) ^ ax) << 4);             // A chunk byte (lo)

    f32x4 acc[2][8] = {};
    __syncthreads();

    int buf = 0;
    for (int t = 0; t < 16; t++) {
        const int nb = (buf ^ 1) * 24576;
        if (t < 15) {
            gl16(aP,          aD + nb);
            gl16(aP + 16384,  aD + nb + 1024);
            gl16(aP + 32768,  aD + nb + 2048);
            gl16(aP + 49152,  aD + nb + 3072);
            gl16(bP,          bD + nb);
            gl16(bP + 16384,  bD + nb + 1024);
            aP += 128; bP += 64;
        }
        const char* sA = smem + buf * 24576;
        const char* sB = sA + 16384;

        f16x8 a[2];
#pragma unroll
        for (int rt = 0; rt < 2; rt++) {
            const int ab = arow0 + rt * 2048;
            f32x4 lo = *(const f32x4*)(sA + ab + ac0);
            f32x4 hi = *(const f32x4*)(sA + ab + (ac0 ^ 16));
            a[rt][0] = (f16)lo[0]; a[rt][1] = (f16)lo[1];
            a[rt][2] = (f16)lo[2]; a[rt][3] = (f16)lo[3];
            a[rt][4] = (f16)hi[0]; a[rt][5] = (f16)hi[1];
            a[rt][6] = (f16)hi[2]; a[rt][7] = (f16)hi[3];
        }
#pragma unroll
        for (int half = 0; half < 2; half++) {
            f16x8 b[4];
#pragma unroll
            for (int c = 0; c < 4; c++)
                b[c] = *(const f16x8*)(sB + ((half * 4 + c) * 16 + l15) * 64 + fsw);
#pragma unroll
            for (int rt = 0; rt < 2; rt++)
#pragma unroll
                for (int c = 0; c < 4; c++)
                    acc[rt][half * 4 + c] = __builtin_amdgcn_mfma_f32_16x16x32_f16(
                        a[rt], b[c], acc[rt][half * 4 + c], 0, 0, 0);
        }
        __syncthreads();
        buf ^= 1;
    }

    const int b    = (int)(r0 >> 11);
    const int rloc = ((int)(r0 & 2047)) + wave * 32;

#pragma unroll
    for (int rt = 0; rt < 2; rt++)
#pragma unroll
        for (int ct = 0; ct < 8; ct++) {
            const int col = c0 + ct * 16 + l15;
            if (isQ || col < 512) {
                const int h = (col >> 6) & 7;
                const int d = col & 63;
                f16* dst = isQ ? qws : kws;
                const float sc = isQ ? QSCALE : 1.0f;
#pragma unroll
                for (int reg = 0; reg < 4; reg++) {
                    const int nn = rloc + rt * 16 + quad * 4 + reg;
                    dst[(((size_t)b * 8 + h) * 2048 + nn) * 64 + d] =
                        (f16)(tanhf(acc[rt][ct][reg]) * sc);
                }
            } else {
                const int c = col - 512;
                const int h = c >> 6;
                const int d = c & 63;
                const int m0 = rloc + rt * 16 + quad * 4;
                f16x4 pk;
#pragma unroll
                for (int reg = 0; reg < 4; reg++) pk[reg] = (f16)acc[rt][ct][reg];
                *(f16x4*)(vt + (((size_t)b * 8 + h) * 64 + d) * 2048 + m0) = pk;
            }
        }
}

// ---------------------------------------------------------------------------
// MFMA fp16 flash attention (v9, proven 58.3us): gl16 DMA staging into a
// linear double-buffered LDS with one __syncthreads per 64-j tile; mask
// loads + prefetch issued before compute so their latency hides under it.
// Source-side XOR swizzle (chunk ^ row&7) <-> matching read-side XOR.
// ---------------------------------------------------------------------------
__launch_bounds__(256, 4)
__global__ void attn_k(const f16* __restrict__ qws, const f16* __restrict__ kws,
                       const f16* __restrict__ vtws,
                       const int* __restrict__ mask, const int* __restrict__ cmask,
                       const float* __restrict__ nk, const float* __restrict__ nv,
                       f16* __restrict__ Opf, float* __restrict__ lp)
{
    __shared__ __align__(16) char smem[32768];   // [2][ K:8192 | V:8192 ]

    const int tid  = threadIdx.x;
    const int wave = tid >> 6, lane = tid & 63;
    const int l15  = lane & 15, quad = lane >> 4;
    const int bh = blockIdx.x, b = bh >> 3, h = bh & 7;
    const int q0 = blockIdx.y * 128 + wave * 32;
    const int jh = blockIdx.z;
    const int jbeg = jh << 9, jend = jbeg + 512;

    const f16* kg0 = kws + (size_t)bh * MM * DH;
    const f16* vg0 = vtws + (size_t)bh * DH * MM;

    const int lrow = lane >> 3;
    const int lsw  = ((lane & 7) ^ lrow) << 4;
    const char* kP = (const char*)kg0 + (size_t)(jbeg + wave * 16 + lrow) * 128 + lsw;
    const char* vP = (const char*)vg0 + (size_t)(wave * 16 + lrow) * 4096
                   + (size_t)jbeg * 2 + lsw;
    char* kD = smem + wave * 2048;
    char* vD = smem + 8192 + wave * 2048;

    gl16(kP,         kD);
    gl16(kP + 1024,  kD + 1024);
    gl16(vP,         vD);
    gl16(vP + 32768, vD + 1024);
    kP += 8192; vP += 128;

    f16x8 qf[2][2];
    const f16* qbase = qws + ((size_t)bh * NN + q0) * DH;
#pragma unroll
    for (int rt = 0; rt < 2; rt++)
#pragma unroll
        for (int ks = 0; ks < 2; ks++)
            qf[rt][ks] = *(const f16x8*)(qbase + (rt * 16 + l15) * DH + ks * 32 + quad * 8);

    int rowOk[2];
#pragma unroll
    for (int rt = 0; rt < 2; rt++)
        rowOk[rt] = mask[(size_t)b * NN + q0 + rt * 16 + l15];

    float pnull[2] = {0.0f, 0.0f};
    if (jh == 0) {
        float pn[2] = {0.f, 0.f};
#pragma unroll
        for (int ks = 0; ks < 2; ks++)
#pragma unroll
            for (int t = 0; t < 8; t++) {
                const float nkt = tanhf(nk[ks * 32 + quad * 8 + t]);
                pn[0] += (float)qf[0][ks][t] * nkt;
                pn[1] += (float)qf[1][ks][t] * nkt;
            }
#pragma unroll
        for (int rt = 0; rt < 2; rt++) {
            pn[rt] += __shfl_xor(pn[rt], 16);
            pn[rt] += __shfl_xor(pn[rt], 32);
            pnull[rt] = rowOk[rt] ? EXP2(pn[rt]) : 1.0f;
        }
    }
    float negsel[2];
#pragma unroll
    for (int rt = 0; rt < 2; rt++) {
        negsel[rt] = rowOk[rt] ? -1.0e30f : 0.0f;
        if (!rowOk[rt]) {
            const f16x8 zz = {(f16)0, (f16)0, (f16)0, (f16)0, (f16)0, (f16)0, (f16)0, (f16)0};
            qf[rt][0] = zz; qf[rt][1] = zz;
        }
    }

    f32x4 acc[2][4];
    f32x4 accl[2];
#pragma unroll
    for (int rt = 0; rt < 2; rt++)
#pragma unroll
        for (int reg = 0; reg < 4; reg++) {
            const float pr = __shfl(pnull[rt], quad * 4 + reg, 16);
            accl[rt][reg] = pr;
#pragma unroll
            for (int ds = 0; ds < 4; ds++)
                acc[rt][ds][reg] = pr * nv[ds * 16 + l15];
        }

    const f16x4 vone = {(f16)1, (f16)1, (f16)1, (f16)1};
    const int kxor = l15 & 7;

    __syncthreads();

    int buf = 0;
    for (int jc = jbeg; jc < jend; jc += 64) {
        int4 cmv[4];
#pragma unroll
        for (int jj = 0; jj < 4; jj++)
            cmv[jj] = *(const int4*)(cmask + (size_t)b * MM + jc + jj * 16 + quad * 4);

        if (jc + 64 < jend) {
            const int bo = (buf ^ 1) << 14;
            gl16(kP,         kD + bo);
            gl16(kP + 1024,  kD + bo + 1024);
            gl16(vP,         vD + bo);
            gl16(vP + 32768, vD + bo + 1024);
            kP += 8192; vP += 128;
        }

        const char* sKb = smem + (buf << 14);
        const char* sVb = sKb + 8192;

        f32x4 st[2][4];
#pragma unroll
        for (int rt = 0; rt < 2; rt++)
#pragma unroll
            for (int jj = 0; jj < 4; jj++) {
                st[rt][jj][0] = cmv[jj].x ? 0.0f : negsel[rt];
                st[rt][jj][1] = cmv[jj].y ? 0.0f : negsel[rt];
                st[rt][jj][2] = cmv[jj].z ? 0.0f : negsel[rt];
                st[rt][jj][3] = cmv[jj].w ? 0.0f : negsel[rt];
            }

#pragma unroll
        for (int ks = 0; ks < 2; ks++) {
            f16x8 kb[4];
#pragma unroll
            for (int jj = 0; jj < 4; jj++)
                kb[jj] = *(const f16x8*)(sKb + (jj * 16 + l15) * 128
                                             + (((ks * 4 + quad) ^ kxor) << 4));
#pragma unroll
            for (int rt = 0; rt < 2; rt++)
#pragma unroll
                for (int jj = 0; jj < 4; jj++)
                    st[rt][jj] = __builtin_amdgcn_mfma_f32_16x16x32_f16(
                        kb[jj], qf[rt][ks], st[rt][jj], 0, 0, 0);
        }

        f16x4 pa[2][4];
#pragma unroll
        for (int rt = 0; rt < 2; rt++)
#pragma unroll
            for (int jj = 0; jj < 4; jj++)
                pa[rt][jj] = pk4(EXP2(st[rt][jj][0]), EXP2(st[rt][jj][1]),
                                 EXP2(st[rt][jj][2]), EXP2(st[rt][jj][3]));

#pragma unroll
        for (int jj = 0; jj < 4; jj++) {
            f16x4 vb[4];
#pragma unroll
            for (int ds = 0; ds < 4; ds++)
                vb[ds] = *(const f16x4*)(sVb + (ds * 16 + l15) * 128
                                             + (((jj * 2 + (quad >> 1)) ^ kxor) << 4)
                                             + ((quad & 1) << 3));
#pragma unroll
            for (int rt = 0; rt < 2; rt++) {
#pragma unroll
                for (int ds = 0; ds < 4; ds++)
                    acc[rt][ds] = __builtin_amdgcn_mfma_f32_16x16x16f16(
                        pa[rt][jj], vb[ds], acc[rt][ds], 0, 0, 0);
                accl[rt] = __builtin_amdgcn_mfma_f32_16x16x16f16(
                    pa[rt][jj], vone, accl[rt], 0, 0, 0);
            }
        }

        __syncthreads();
        buf ^= 1;
    }

    // epilogue: normalized f16 partials + l
#pragma unroll
    for (int rt = 0; rt < 2; rt++) {
        float inv[4];
#pragma unroll
        for (int reg = 0; reg < 4; reg++)
            inv[reg] = 1.0f / fmaxf(accl[rt][reg], 1e-35f);
#pragma unroll
        for (int ds = 0; ds < 4; ds++)
#pragma unroll
            for (int reg = 0; reg < 4; reg++) {
                const int r = q0 + rt * 16 + quad * 4 + reg;
                Opf[((size_t)jh * 8192 + b * 2048 + r) * 512 + h * 64 + ds * 16 + l15] =
                    (f16)(acc[rt][ds][reg] * inv[reg]);
            }
    }
    if (l15 == 0) {
#pragma unroll
        for (int rt = 0; rt < 2; rt++)
#pragma unroll
            for (int reg = 0; reg < 4; reg++)
                lp[((size_t)jh * 32 + bh) * 2048 + q0 + rt * 16 + quad * 4 + reg] =
                    accl[rt][reg];
    }
}

// ---------------------------------------------------------------------------
// Merge 4 j-partials: O = sum(Ohat_p * l_p) / sum(l_p) -> f16 of16.
// ---------------------------------------------------------------------------
__global__ void merge_k(const f16* __restrict__ Opf, const float* __restrict__ lp,
                        f16* __restrict__ of16)
{
    const int i = blockIdx.x * 256 + threadIdx.x;   // 1,048,576 threads
    const int row = i >> 7;                          // 0..8191
    const int c4  = i & 127;
    const int b = row >> 11, n = row & 2047, h = c4 >> 4;
    float w[4], den = 0.f;
#pragma unroll
    for (int jh = 0; jh < 4; jh++) {
        w[jh] = lp[((size_t)jh * 32 + b * 8 + h) * 2048 + n];
        den += w[jh];
    }
    const float inv = 1.0f / den;
    float v0 = 0, v1 = 0, v2 = 0, v3 = 0;
#pragma unroll
    for (int jh = 0; jh < 4; jh++) {
        f16x4 o = *(const f16x4*)(Opf + ((size_t)jh * 8192 + row) * 512 + c4 * 4);
        v0 += (float)o[0] * w[jh];
        v1 += (float)o[1] * w[jh];
        v2 += (float)o[2] * w[jh];
        v3 += (float)o[3] * w[jh];
    }
    f16x4 r = pk4(v0 * inv, v1 * inv, v2 * inv, v3 * inv);
    *(f16x4*)(of16 + (size_t)row * 512 + c4 * 4) = r;
}

// ---------------------------------------------------------------------------
// Final GEMM v3: out = O(f16) @ Wo(f16 hi/lo) + bias. 128x64 tiles,
// grid (64,8) = 512 blocks = 2 blocks/CU (v2's grid(64,4) was 1/CU — no
// latency hiding). gl16 DMA staging, linear dbuf LDS 2x16KB, one barrier
// per k-step, 16 MFMA/k-step/wave.
// ---------------------------------------------------------------------------
__launch_bounds__(256, 4)
__global__ void mgemm2(const f16* __restrict__ A, const f16* __restrict__ Bh,
                       const f16* __restrict__ Bl,
                       float* __restrict__ o32, const float* __restrict__ bias,
                       int K)
{
    __shared__ __align__(16) char smem[32768];   // 2 x [A:8KB | Bh:4KB | Bl:4KB]

    const int tid  = threadIdx.x;
    const int wave = tid >> 6, lane = tid & 63;
    const int l15  = lane & 15, quad = lane >> 4;
    const size_t r0 = (size_t)blockIdx.x * 128;
    const int c0 = blockIdx.y * 64;

    // A: 2 gl16/wave (rows wave*32 + i*16 + (lane>>2)); Bh/Bl: 1 gl16/wave
    // (rows wave*16 + (lane>>2)). chunk = lane&3, src chunk ^= ((row>>1)&3).
    const int blr = lane >> 2;
    const int bsw = (lane & 3) ^ ((lane >> 3) & 3);
    const char* aP = (const char*)(A + (r0 + wave * 32 + blr) * K) + bsw * 16;
    const char* hP = (const char*)(Bh + (size_t)(c0 + wave * 16 + blr) * K) + bsw * 16;
    const char* lP = (const char*)(Bl + (size_t)(c0 + wave * 16 + blr) * K) + bsw * 16;
    char* aD = smem + wave * 2048;
    char* hD = smem + 8192 + wave * 1024;
    char* lD = smem + 12288 + wave * 1024;

    gl16(aP,          aD);
    gl16(aP + 16384,  aD + 1024);   // +16 rows (16*512*2 B)
    gl16(hP,          hD);
    gl16(lP,          lD);
    aP += 64; hP += 64; lP += 64;

    const int fsw = ((quad ^ ((l15 >> 1) & 3)) << 4);
    const int aoff0 = (wave * 32 + l15) * 64 + fsw;
    const int aoff1 = aoff0 + 16 * 64;

    f32x4 acc[2][4] = {};
    __syncthreads();

    int buf = 0;
    const int NT = K / 32;
    for (int t = 0; t < NT; t++) {
        const int nb = (buf ^ 1) * 16384;
        if (t < NT - 1) {
            gl16(aP,          aD + nb);
            gl16(aP + 16384,  aD + nb + 1024);
            gl16(hP,          hD + nb);
            gl16(lP,          lD + nb);
            aP += 64; hP += 64; lP += 64;
        }
        const char* sA = smem + buf * 16384;
        const char* sH = sA + 8192;
        const char* sL = sA + 12288;

        f16x8 a[2];
        a[0] = *(const f16x8*)(sA + aoff0);
        a[1] = *(const f16x8*)(sA + aoff1);
#pragma unroll
        for (int ct = 0; ct < 4; ct++) {
            const int boff = (ct * 16 + l15) * 64 + fsw;
            f16x8 bh = *(const f16x8*)(sH + boff);
            f16x8 bl = *(const f16x8*)(sL + boff);
#pragma unroll
            for (int rt = 0; rt < 2; rt++) {
                acc[rt][ct] = __builtin_amdgcn_mfma_f32_16x16x32_f16(
                    a[rt], bh, acc[rt][ct], 0, 0, 0);
                acc[rt][ct] = __builtin_amdgcn_mfma_f32_16x16x32_f16(
                    a[rt], bl, acc[rt][ct], 0, 0, 0);
            }
        }
        __syncthreads();
        buf ^= 1;
    }

#pragma unroll
    for (int rt = 0; rt < 2; rt++)
#pragma unroll
        for (int ct = 0; ct < 4; ct++) {
            const int col = c0 + ct * 16 + l15;
            const float bv = bias[col];
#pragma unroll
            for (int reg = 0; reg < 4; reg++) {
                const size_t row = r0 + wave * 32 + rt * 16 + quad * 4 + reg;
                o32[row * 512 + col] = acc[rt][ct][reg] + bv;
            }
        }
}

extern "C" void kernel_launch(void* const* d_in, const int* in_sizes, int n_in,
                              void* d_out, int out_size, void* d_ws, size_t ws_size,
                              hipStream_t stream)
{
    const float* x    = (const float*)d_in[0];
    const float* ctx  = (const float*)d_in[1];
    const int*   mask = (const int*)d_in[2];
    const int*   cmsk = (const int*)d_in[3];
    const float* Wq   = (const float*)d_in[4];
    const float* Wkv  = (const float*)d_in[5];
    const float* Wo   = (const float*)d_in[6];
    const float* bo   = (const float*)d_in[7];
    const float* nk   = (const float*)d_in[8];
    const float* nv   = (const float*)d_in[9];
    float* out = (float*)d_out;

    const size_t S = (size_t)BB * HEADS * NN * DH;  // 4,194,304 elems

    f16* qws = (f16*)d_ws;                  // 8 MB
    f16* kws = qws + S;                     // 8 MB
    f16* vt  = kws + S;                     // 8 MB
    f16* wq16  = vt + S;                    // 0.5 MB
    f16* wkv16 = wq16 + 512 * 512;          // 1 MB
    f16* woh = wkv16 + 512 * 1024;          // 0.5 MB
    f16* wol = woh + 512 * 512;             // 0.5 MB
    float* lp = (float*)(wol + 512 * 512);  // 1 MB
    f16* Opf = (f16*)(lp + 4 * 32 * 2048);  // 32 MB
    f16* of16 = qws;                        // alias (qws dead after attn_k)

    wprep_k<<<512, 256, 0, stream>>>(Wq, Wkv, Wo, wq16, wkv16, woh, wol);
    proj_k<<<dim3(64, 12), 256, 0, stream>>>(x, ctx, wq16, wkv16, qws, kws, vt);
    attn_k<<<dim3(32, 16, 4), 256, 0, stream>>>(qws, kws, vt, mask, cmsk, nk, nv, Opf, lp);
    merge_k<<<4096, 256, 0, stream>>>(Opf, lp, of16);
    mgemm2<<<dim3(64, 8), 256, 0, stream>>>(of16, woh, wol, out, bo, 512);
}